// Round 5
// baseline (1977.881 us; speedup 1.0000x reference)
//
#include <hip/hip_runtime.h>

// Problem constants
#define BATCH   32
#define CPD     64
#define TSTEPS  1024
#define IN_DIM  256
#define HID     512
#define WIN     1024

typedef _Float16 half2_t __attribute__((ext_vector_type(2)));
typedef _Float16 f16x8   __attribute__((ext_vector_type(8)));
typedef float    f32x4   __attribute__((ext_vector_type(4)));

union F16x8U { f16x8 v; half2_t p[4]; };

__device__ __forceinline__ float tanh_fast(float x) {
    // tanh(x) = 1 - 2/(e^{2x}+1); exact at +-inf, ~1e-7 abs err in range
    float e = __expf(2.0f * x);
    return 1.0f - 2.0f / (e + 1.0f);
}

// DPP cross-lane mov: returns partner lane's x per CTRL (within 16-lane row)
template <int CTRL>
__device__ __forceinline__ float dpp_xor_f32(float x) {
    return __int_as_float(
        __builtin_amdgcn_update_dpp(0, __float_as_int(x), CTRL, 0xf, 0xf, true));
}
#define DPP_XOR1 0xB1   // quad_perm [1,0,3,2]
#define DPP_XOR2 0x4E   // quad_perm [2,3,0,1]
#define DPP_XOR8 0x128  // row_ror:8  (== xor8 within 16-lane row)

// ---------------- A1: M_t[h][c] = sum_i proj[c][i] * W_ih[h][i] ----------------
__global__ __launch_bounds__(512) void k_a1(const float* __restrict__ proj,
                                            const float* __restrict__ W_ih,
                                            float* __restrict__ M_t) {
    __shared__ float p[IN_DIM];
    int c = blockIdx.x;                       // 64 blocks
    if (threadIdx.x < IN_DIM) p[threadIdx.x] = proj[c * IN_DIM + threadIdx.x];
    __syncthreads();
    int h = threadIdx.x;                      // 512 threads
    const float4* wr = (const float4*)(W_ih + (size_t)h * IN_DIM);
    float acc = 0.f;
#pragma unroll
    for (int i = 0; i < IN_DIM / 4; ++i) {
        float4 v = wr[i];
        acc += v.x * p[4*i] + v.y * p[4*i+1] + v.z * p[4*i+2] + v.w * p[4*i+3];
    }
    M_t[(size_t)h * CPD + c] = acc;           // [512][64]
}

// ---------------- C0: convert W_out f32 -> f16 ----------------
__global__ __launch_bounds__(256) void k_cvt(const float* __restrict__ src,
                                             _Float16* __restrict__ dst) {
    int i = (blockIdx.x * 256 + threadIdx.x) * 4;   // 512 blocks covers 524288
    float4 v = *(const float4*)(src + i);
    dst[i+0] = (_Float16)v.x; dst[i+1] = (_Float16)v.y;
    dst[i+2] = (_Float16)v.z; dst[i+3] = (_Float16)v.w;
}

// ---------------- A2: xw[b][t][h] = sum_c control[b][c][t] * M_t[h][c] ----------------
__global__ __launch_bounds__(512) void k_a2(const float* __restrict__ control,
                                            const float* __restrict__ M_t,
                                            float* __restrict__ xw) {
    __shared__ float ctl[CPD][68];            // padded, 16B-aligned rows
    int b  = blockIdx.x >> 4;                 // 32 batches
    int t0 = (blockIdx.x & 15) * 64;          // 16 t-blocks of 64
    int tid = threadIdx.x;                    // 512 threads

    // stage control tile (64 c x 64 t), coalesced float4 along t
    const float* gb = control + (size_t)b * CPD * TSTEPS + t0;
#pragma unroll
    for (int i = 0; i < 2; ++i) {
        int flat4 = tid * 2 + i;              // 0..1023 quads
        int c = flat4 >> 4, t4 = (flat4 & 15) * 4;
        float4 v = *(const float4*)(gb + (size_t)c * TSTEPS + t4);
        *(float4*)&ctl[c][t4] = v;
    }
    // M row into regs
    int h = tid;
    float mrow[CPD];
    const float4* mp = (const float4*)(M_t + (size_t)h * CPD);
#pragma unroll
    for (int i = 0; i < CPD / 4; ++i) {
        float4 v = mp[i];
        mrow[4*i] = v.x; mrow[4*i+1] = v.y; mrow[4*i+2] = v.z; mrow[4*i+3] = v.w;
    }
    __syncthreads();

    float* xo = xw + ((size_t)b * TSTEPS + t0) * HID + h;
#pragma unroll
    for (int half = 0; half < 2; ++half) {
        float acc[32];
#pragma unroll
        for (int q = 0; q < 32; ++q) acc[q] = 0.f;
#pragma unroll
        for (int c = 0; c < CPD; ++c) {
            float m = mrow[c];
#pragma unroll
            for (int q = 0; q < 8; ++q) {
                float4 v = *(const float4*)&ctl[c][half * 32 + q * 4];  // broadcast read
                acc[q*4+0] += v.x * m; acc[q*4+1] += v.y * m;
                acc[q*4+2] += v.z * m; acc[q*4+3] += v.w * m;
            }
        }
#pragma unroll
        for (int tt = 0; tt < 32; ++tt)
            xo[(size_t)(half * 32 + tt) * HID] = acc[tt];
    }
}

// ---------------- B: sequential recurrence, one WG per batch ----------------
// 32 WGs x 512 threads, waves_per_eu(2,2) -> 256-reg budget, 1 WG/CU (LDS).
// Thread tid = rb*16+cs owns W rows [rb*16, rb*16+16) x cols [cs*32, cs*32+32).
// Rows 0..11 in ARCH VGPRs (192 half2) -- pinned by inline-asm "v" constraints
// on v_dot2_f32_f16 (round-4 post-mortem: plain builtins let the allocator put
// half the weights in AGPRs; VOP3P can't source AGPRs -> accvgpr_read per use,
// ~2x VALU inflation). Rows 12..15 stream from LDS ([chunk][tid] f16x8 ->
// conflict-free b128). Per step: 256 dot2 -> 4-stage distributed xor-reduce
// (DPP xor1/2/8, shfl xor4); final row == tid -> coalesced xw load/hs store.
#define HB_STRIDE 40

// One h-word (half2) against 12 VGPR rows (col K, literal) + 4 LDS-row words
#define DOTCOL(HW, K, U12, U13, U14, U15)                                     \
    {                                                                         \
        half2_t hh = __builtin_bit_cast(half2_t, (unsigned)(HW));             \
        _Pragma("unroll")                                                     \
        for (int j = 0; j < 12; ++j)                                          \
            asm("v_dot2_f32_f16 %0, %1, %2, %3"                               \
                : "=v"(a[j]) : "v"(wreg[j][K]), "v"(hh), "v"(a[j]));          \
        asm("v_dot2_f32_f16 %0, %1, %2, %3"                                   \
            : "=v"(a[12])                                                     \
            : "v"(__builtin_bit_cast(half2_t, (unsigned)(U12))), "v"(hh),     \
              "v"(a[12]));                                                    \
        asm("v_dot2_f32_f16 %0, %1, %2, %3"                                   \
            : "=v"(a[13])                                                     \
            : "v"(__builtin_bit_cast(half2_t, (unsigned)(U13))), "v"(hh),     \
              "v"(a[13]));                                                    \
        asm("v_dot2_f32_f16 %0, %1, %2, %3"                                   \
            : "=v"(a[14])                                                     \
            : "v"(__builtin_bit_cast(half2_t, (unsigned)(U14))), "v"(hh),     \
              "v"(a[14]));                                                    \
        asm("v_dot2_f32_f16 %0, %1, %2, %3"                                   \
            : "=v"(a[15])                                                     \
            : "v"(__builtin_bit_cast(half2_t, (unsigned)(U15))), "v"(hh),     \
              "v"(a[15]));                                                    \
    }

#define QBLOCK(QQ)                                                            \
    {                                                                         \
        uint4 hu  = *(const uint4*)(rp + (QQ) * 8);                           \
        uint4 u12 = *(const uint4*)&wlds[((0 * 4 + (QQ)) << 9) + tid];        \
        uint4 u13 = *(const uint4*)&wlds[((1 * 4 + (QQ)) << 9) + tid];        \
        uint4 u14 = *(const uint4*)&wlds[((2 * 4 + (QQ)) << 9) + tid];        \
        uint4 u15 = *(const uint4*)&wlds[((3 * 4 + (QQ)) << 9) + tid];        \
        DOTCOL(hu.x, (QQ) * 4 + 0, u12.x, u13.x, u14.x, u15.x)                \
        DOTCOL(hu.y, (QQ) * 4 + 1, u12.y, u13.y, u14.y, u15.y)                \
        DOTCOL(hu.z, (QQ) * 4 + 2, u12.z, u13.z, u14.z, u15.z)                \
        DOTCOL(hu.w, (QQ) * 4 + 3, u12.w, u13.w, u14.w, u15.w)                \
    }

__global__ __launch_bounds__(512, 2)
__attribute__((amdgpu_waves_per_eu(2, 2)))
void k_scan(const float* __restrict__ W_hh,
            const float* __restrict__ xw,
            _Float16* __restrict__ hs) {
    const int b    = blockIdx.x;
    const int tid  = threadIdx.x;             // 512
    const int cs   = tid & 15;                // col slice
    const int rb   = tid >> 4;                // row block (16 rows)
    const int lane = tid & 63;

    // LDS: wlds[16][512] f16x8 (128 KiB) + h double buffer (~2.6 KiB)
    __shared__ __align__(16) f16x8    wlds[16 * 512];
    __shared__ __align__(16) _Float16 hb[2][16 * HB_STRIDE + 8];

    // ---- rows 0..11 into VGPRs: wreg[j][q] = W[rb*16+j][cs*32+2q..+1] ----
    half2_t wreg[12][16];
#pragma unroll
    for (int j = 0; j < 12; ++j) {
        const float* src = W_hh + (size_t)(rb * 16 + j) * HID + cs * 32;
#pragma unroll
        for (int q = 0; q < 16; q += 2) {
            float4 f = *(const float4*)(src + 2 * q);
            wreg[j][q]     = (half2_t){(_Float16)f.x, (_Float16)f.y};
            wreg[j][q + 1] = (half2_t){(_Float16)f.z, (_Float16)f.w};
        }
    }
    // ---- rows 12..15 into LDS: chunk r*4+qq holds cols [qq*8, qq*8+8) ----
#pragma unroll
    for (int r = 0; r < 4; ++r) {
        const float* src = W_hh + (size_t)(rb * 16 + 12 + r) * HID + cs * 32;
#pragma unroll
        for (int qq = 0; qq < 4; ++qq) {
            float4 f0 = *(const float4*)(src + qq * 8);
            float4 f1 = *(const float4*)(src + qq * 8 + 4);
            F16x8U u;
            u.p[0] = (half2_t){(_Float16)f0.x, (_Float16)f0.y};
            u.p[1] = (half2_t){(_Float16)f0.z, (_Float16)f0.w};
            u.p[2] = (half2_t){(_Float16)f1.x, (_Float16)f1.y};
            u.p[3] = (half2_t){(_Float16)f1.z, (_Float16)f1.w};
            wlds[((r * 4 + qq) << 9) + tid] = u.v;
        }
    }

    const bool b0 = lane & 1, b1 = lane & 2, b2 = lane & 4, b3 = lane & 8;
    const float* xwb = xw + (size_t)b * TSTEPS * HID;
    _Float16*    hsb = hs + (size_t)b * TSTEPS * HID;
    const int hbpos = (tid >> 5) * HB_STRIDE + (tid & 31);   // row 'tid' slot

    // ---- t = 0: h0 = tanh(xw[0][tid]) ----
    {
        float h0 = tanh_fast(xwb[tid]);
        _Float16 hf = (_Float16)h0;
        hb[0][hbpos] = hf;
        hsb[tid] = hf;
    }
    __syncthreads();

#pragma unroll 1
    for (int t = 1; t < TSTEPS; ++t) {
        // prefetch xw[t][tid] (consumed after the dot+reduce)
        float xwv = xwb[(size_t)t * HID + tid];

        const _Float16* rp = &hb[(t + 1) & 1][cs * HB_STRIDE];

        float a[16];
#pragma unroll
        for (int j = 0; j < 16; ++j) a[j] = 0.f;

        // ---- dot: a[i] = W[rb*16+i][cs*32..+32) . h[cs*32..+32) ----
        QBLOCK(0) QBLOCK(1) QBLOCK(2) QBLOCK(3)

        // ---- 4-stage distributed xor-reduce over 16 col-slices ----
        // final: a[0] = full sum of row rb*16 + (lane&15) == tid
#pragma unroll
        for (int j = 0; j < 8; ++j) {          // xor1 (DPP quad_perm)
            float snd = b0 ? a[2 * j] : a[2 * j + 1];
            float kp  = b0 ? a[2 * j + 1] : a[2 * j];
            a[j] = kp + dpp_xor_f32<DPP_XOR1>(snd);
        }
#pragma unroll
        for (int j = 0; j < 4; ++j) {          // xor2 (DPP quad_perm)
            float snd = b1 ? a[2 * j] : a[2 * j + 1];
            float kp  = b1 ? a[2 * j + 1] : a[2 * j];
            a[j] = kp + dpp_xor_f32<DPP_XOR2>(snd);
        }
#pragma unroll
        for (int j = 0; j < 2; ++j) {          // xor4 (ds_swizzle via shfl)
            float snd = b2 ? a[2 * j] : a[2 * j + 1];
            float kp  = b2 ? a[2 * j + 1] : a[2 * j];
            a[j] = kp + __shfl_xor(snd, 4, 64);
        }
        {                                      // xor8 (DPP row_ror:8)
            float snd = b3 ? a[0] : a[1];
            float kp  = b3 ? a[1] : a[0];
            a[0] = kp + dpp_xor_f32<DPP_XOR8>(snd);
        }

        // ---- activation + publish (row == tid: fully coalesced) ----
        float hval = tanh_fast(a[0] + xwv);
        _Float16 hfv = (_Float16)hval;
        hb[t & 1][hbpos] = hfv;
        hsb[(size_t)t * HID + tid] = hfv;
        __syncthreads();
    }
}

// ---------------- C: out[row][w] = sin( sum_h hs[row][h] * Wout[w][h] ) ----------------
// 128x128 tile, BK=32, 4 waves in 2x2 quadrants, f16 MFMA 16x16x32.
// Grid is (N-tiles, M-tiles) so consecutive blocks share the A panel (L2 reuse).
__global__ void k_outgemm(const _Float16* __restrict__ hs,
                          const _Float16* __restrict__ Wo,
                          float* __restrict__ out) {
    __shared__ _Float16 Ap[128][40];          // +8 pad: conflict-free frag reads
    __shared__ _Float16 Bp[128][40];
    int tid = threadIdx.x;
    int r0 = blockIdx.y * 128;                // 256 M-tiles
    int c0 = blockIdx.x * 128;                // 8 N-tiles
    int wid = tid >> 6, l = tid & 63;
    int wr = (wid >> 1) * 64, wc = (wid & 1) * 64;
    int lrow = tid & 127, lhalf = (tid >> 7) * 16;   // staging assignment
    int fr = l & 15, kg = (l >> 4) * 8;

    f32x4 acc[4][4];
#pragma unroll
    for (int m = 0; m < 4; ++m)
#pragma unroll
        for (int n = 0; n < 4; ++n) acc[m][n] = (f32x4){0.f, 0.f, 0.f, 0.f};

    for (int k0 = 0; k0 < HID; k0 += 32) {
        const uint4* ga = (const uint4*)(hs + (size_t)(r0 + lrow) * HID + k0 + lhalf);
        uint4 a0 = ga[0], a1 = ga[1];
        const uint4* gbp = (const uint4*)(Wo + (size_t)(c0 + lrow) * HID + k0 + lhalf);
        uint4 b0 = gbp[0], b1 = gbp[1];
        __syncthreads();                      // prev-iter reads done
        *(uint4*)&Ap[lrow][lhalf] = a0; *(uint4*)&Ap[lrow][lhalf + 8] = a1;
        *(uint4*)&Bp[lrow][lhalf] = b0; *(uint4*)&Bp[lrow][lhalf + 8] = b1;
        __syncthreads();

        f16x8 af[4], bf[4];
#pragma unroll
        for (int m = 0; m < 4; ++m) af[m] = *(const f16x8*)&Ap[wr + m * 16 + fr][kg];
#pragma unroll
        for (int n = 0; n < 4; ++n) bf[n] = *(const f16x8*)&Bp[wc + n * 16 + fr][kg];
#pragma unroll
        for (int m = 0; m < 4; ++m)
#pragma unroll
            for (int n = 0; n < 4; ++n)
                acc[m][n] = __builtin_amdgcn_mfma_f32_16x16x32_f16(af[m], bf[n], acc[m][n], 0, 0, 0);
    }

    int fq = l >> 4;
#pragma unroll
    for (int m = 0; m < 4; ++m)
#pragma unroll
        for (int n = 0; n < 4; ++n)
#pragma unroll
            for (int q = 0; q < 4; ++q) {
                int row = r0 + wr + m * 16 + fq * 4 + q;
                int col = c0 + wc + n * 16 + fr;
                out[(size_t)row * WIN + col] = __sinf(acc[m][n][q]);
            }
}

// ---------------- launch ----------------
extern "C" void kernel_launch(void* const* d_in, const int* in_sizes, int n_in,
                              void* d_out, int out_size, void* d_ws, size_t ws_size,
                              hipStream_t stream) {
    const float* control = (const float*)d_in[0];  // (32, 64, 1024)
    const float* proj    = (const float*)d_in[1];  // (64, 256)
    const float* W_ih    = (const float*)d_in[2];  // (512, 256)
    const float* W_hh    = (const float*)d_in[3];  // (512, 512)
    const float* W_out   = (const float*)d_in[4];  // (1024, 512)
    float* out = (float*)d_out;                    // 32 * 1024 * 1024 f32

    // workspace carve
    const size_t XW_B   = (size_t)BATCH * TSTEPS * HID * 4;     // 64 MiB
    const size_t MT_B   = (size_t)HID * CPD * 4;                // 128 KiB
    const size_t HS_B   = (size_t)BATCH * TSTEPS * HID * 2;     // 32 MiB
    const size_t WO_B   = (size_t)WIN * HID * 2;                // 1 MiB
    if (ws_size < XW_B + MT_B + HS_B + WO_B) return;

    char* ws = (char*)d_ws;
    float* xw = (float*)ws;                          ws += XW_B;
    float* M_t = (float*)ws;                         ws += MT_B;
    _Float16* hs = (_Float16*)ws;                    ws += HS_B;
    _Float16* Wo = (_Float16*)ws;

    k_a1<<<CPD, 512, 0, stream>>>(proj, W_ih, M_t);
    k_cvt<<<512, 256, 0, stream>>>(W_out, Wo);
    k_a2<<<BATCH * 16, 512, 0, stream>>>(control, M_t, xw);
    k_scan<<<BATCH, 512, 0, stream>>>(W_hh, xw, hs);
    k_outgemm<<<dim3(8, 256), 256, 0, stream>>>(hs, Wo, out);
}